// Round 1
// baseline (99.808 us; speedup 1.0000x reference)
//
#include <hip/hip_runtime.h>

#define NAG   8192
#define NK    4096
#define BLOCK 256
#define CHUNK 512
#define NCK   (NAG / CHUNK)   // 16 KDE chunks
#define NCG   (NK  / CHUNK)   // 8 GMM chunks

// exp(-d2/(2h^2))    = exp2(d2 * C_KDE),  h = 0.05     -> -200*log2(e)
// exp(-d2/(2s^2))    = exp2(d2 * C_GMM),  s = 5/64     -> -81.92*log2(e)
#define C_KDE  (-288.53900817779268f)
#define C_GMM  (-118.18557774962068f)
// out_i = (B_i/h^2 - C_i*N*h^2/s^4 + F_i*N*h^2/s^2) / A_i
#define SC_B   (400.0f)          // 1/h^2
#define SC_C   (549755.813888f)  // N*h^2/s^4 = 20.48 * 16777216/625
#define SC_F   (3355.4432f)      // N*h^2/s^2 = 20.48 * 4096/25

// acc layout per agent: [0]=A [1]=Bx [2]=By [3]=Cx [4]=Cy [5]=Fx [6]=Fy [7]=pad
__global__ __launch_bounds__(BLOCK) void wm_pair_kernel(
    const float*  __restrict__ t,
    const float2* __restrict__ X,
    const float2* __restrict__ m0,
    const float2* __restrict__ mv,
    const float*  __restrict__ w,
    float* __restrict__ acc) {
  __shared__ float4 sP[CHUNK];   // GMM: {mx,my,mvx,mvy}; KDE: reused as float2[CHUNK]
  __shared__ float  sW[CHUNK];

  const int i = blockIdx.x * BLOCK + threadIdx.x;   // agent index
  const float2 Xi = X[i];
  const int c = blockIdx.y;

  if (c < NCK) {
    // ---- KDE chunk: pairs (i, X[base..base+CHUNK)) ----
    float2* sX = reinterpret_cast<float2*>(sP);
    const int base = c * CHUNK;
    for (int j = threadIdx.x; j < CHUNK; j += BLOCK)
      sX[j] = X[base + j];
    __syncthreads();

    float A = 0.f, Bx = 0.f, By = 0.f;
#pragma unroll 8
    for (int j = 0; j < CHUNK; ++j) {
      const float2 p = sX[j];
      const float dx = Xi.x - p.x;
      const float dy = Xi.y - p.y;
      const float d2 = dx * dx + dy * dy;
      const float e  = __builtin_amdgcn_exp2f(d2 * C_KDE);
      A  += e;
      Bx += e * dx;
      By += e * dy;
    }
    atomicAdd(&acc[i * 8 + 0], A);
    atomicAdd(&acc[i * 8 + 1], Bx);
    atomicAdd(&acc[i * 8 + 2], By);
  } else {
    // ---- GMM chunk: pairs (i, component base..base+CHUNK) ----
    const int base = (c - NCK) * CHUNK;
    const float tt = t[0];
    for (int j = threadIdx.x; j < CHUNK; j += BLOCK) {
      const float2 m0j = m0[base + j];
      const float2 mvj = mv[base + j];
      sP[j] = make_float4(m0j.x + mvj.x * tt, m0j.y + mvj.y * tt, mvj.x, mvj.y);
      sW[j] = w[base + j];
    }
    __syncthreads();

    float Cx = 0.f, Cy = 0.f, Fx = 0.f, Fy = 0.f;
#pragma unroll 4
    for (int j = 0; j < CHUNK; ++j) {
      const float4 p  = sP[j];
      const float dx  = Xi.x - p.x;
      const float dy  = Xi.y - p.y;
      const float d2  = dx * dx + dy * dy;
      const float g   = __builtin_amdgcn_exp2f(d2 * C_GMM);
      const float wg  = sW[j] * g;
      Cx += wg * dx;
      Cy += wg * dy;
      Fx += wg * p.z;
      Fy += wg * p.w;
    }
    atomicAdd(&acc[i * 8 + 3], Cx);
    atomicAdd(&acc[i * 8 + 4], Cy);
    atomicAdd(&acc[i * 8 + 5], Fx);
    atomicAdd(&acc[i * 8 + 6], Fy);
  }
}

__global__ __launch_bounds__(BLOCK) void wm_final_kernel(
    const float* __restrict__ acc, float2* __restrict__ out) {
  const int i = blockIdx.x * BLOCK + threadIdx.x;
  const float A    = acc[i * 8 + 0];
  const float invA = 1.0f / A;   // A >= 1 (self term), never zero
  const float ox = (SC_B * acc[i * 8 + 1] - SC_C * acc[i * 8 + 3] + SC_F * acc[i * 8 + 5]) * invA;
  const float oy = (SC_B * acc[i * 8 + 2] - SC_C * acc[i * 8 + 4] + SC_F * acc[i * 8 + 6]) * invA;
  out[i] = make_float2(ox, oy);
}

extern "C" void kernel_launch(void* const* d_in, const int* in_sizes, int n_in,
                              void* d_out, int out_size, void* d_ws, size_t ws_size,
                              hipStream_t stream) {
  const float*  t  = (const float*)d_in[0];
  const float2* X  = (const float2*)d_in[1];
  const float2* m0 = (const float2*)d_in[2];
  const float2* mv = (const float2*)d_in[3];
  const float*  w  = (const float*)d_in[4];
  float* acc = (float*)d_ws;   // NAG*8 floats = 256 KB

  hipMemsetAsync(acc, 0, (size_t)NAG * 8 * sizeof(float), stream);

  dim3 grid(NAG / BLOCK, NCK + NCG);   // 32 x 24 = 768 blocks
  wm_pair_kernel<<<grid, BLOCK, 0, stream>>>(t, X, m0, mv, w, acc);
  wm_final_kernel<<<NAG / BLOCK, BLOCK, 0, stream>>>(acc, (float2*)d_out);
}

// Round 2
// 89.555 us; speedup vs baseline: 1.1145x; 1.1145x over previous
//
#include <hip/hip_runtime.h>

#define NAG   8192
#define NK    4096
#define BLOCK 256
#define CHUNK 256
#define NCK   (NAG / CHUNK)   // 32 KDE chunks
#define NCG   (NK  / CHUNK)   // 16 GMM chunks

// Pre-scale trick: e = exp(-d2/(2h^2)) = exp2(-|sK*dx|^2) with sK = sqrt(log2e/(2h^2)).
// h = 0.05  -> sK^2 = 200*log2e = 288.53900817779268,  sK = 16.98643615
// s = 5/64  -> sG^2 = 81.92*log2e = 118.18557774962069, sG = 10.87131904
#define SK_SCALE 16.98643615f
#define SG_SCALE 10.87131904f
// out_i = (B_i/h^2 - C_i*N*h^2/s^4 + F_i*N*h^2/s^2) / A_i,  with B,C measured in
// prescaled coords (B' = sK*B, C' = sG*C) -> fold 1/sK, 1/sG into the constants:
#define SC_B   (23.5482041f)    // (1/h^2)/sK        = 400/16.98643615
#define SC_C   (50569.375f)     // (N*h^2/s^4)/sG    = 549755.813888/10.87131904
#define SC_F   (3355.4432f)     // N*h^2/s^2 (F uses unscaled mv)

// Workspace layout (no atomics, no zero-init needed; every slot is written):
//   pK: float4[NCK][NAG]  {A, Bx', By', pad}   = 4 MB
//   pG: float4[NCG][NAG]  {Cx', Cy', Fx, Fy}   = 2 MB
__global__ __launch_bounds__(BLOCK) void wm_pair_kernel(
    const float*  __restrict__ t,
    const float2* __restrict__ X,
    const float2* __restrict__ m0,
    const float2* __restrict__ mv,
    const float*  __restrict__ w,
    float4* __restrict__ pK,
    float4* __restrict__ pG) {
  __shared__ float4 sP[CHUNK];   // GMM: {mx'',my'',mvx,mvy}; KDE: reused as float2[CHUNK]
  __shared__ float  sW[CHUNK];

  const int i = blockIdx.x * BLOCK + threadIdx.x;   // agent index
  const float2 Xi = X[i];
  const int c = blockIdx.y;

  if (c < NCK) {
    // ---- KDE chunk ----
    float2* sX = reinterpret_cast<float2*>(sP);
    const int base = c * CHUNK;
    {
      const float2 xj = X[base + threadIdx.x];
      sX[threadIdx.x] = make_float2(xj.x * SK_SCALE, xj.y * SK_SCALE);
    }
    __syncthreads();

    const float xix = Xi.x * SK_SCALE, xiy = Xi.y * SK_SCALE;
    float A = 0.f, Bx = 0.f, By = 0.f;
#pragma unroll 8
    for (int j = 0; j < CHUNK; ++j) {
      const float2 p = sX[j];
      const float dx = xix - p.x;
      const float dy = xiy - p.y;
      const float d2 = __builtin_fmaf(dx, dx, dy * dy);
      const float e  = __builtin_amdgcn_exp2f(-d2);   // neg folds into v_exp_f32 src mod
      A  += e;
      Bx = __builtin_fmaf(e, dx, Bx);
      By = __builtin_fmaf(e, dy, By);
    }
    pK[c * NAG + i] = make_float4(A, Bx, By, 0.f);
  } else {
    // ---- GMM chunk ----
    const int base = (c - NCK) * CHUNK;
    const float tt = t[0];
    {
      const int j = base + threadIdx.x;
      const float2 m0j = m0[j];
      const float2 mvj = mv[j];
      sP[threadIdx.x] = make_float4(__builtin_fmaf(mvj.x, tt, m0j.x) * SG_SCALE,
                                    __builtin_fmaf(mvj.y, tt, m0j.y) * SG_SCALE,
                                    mvj.x, mvj.y);
      sW[threadIdx.x] = w[j];
    }
    __syncthreads();

    const float xix = Xi.x * SG_SCALE, xiy = Xi.y * SG_SCALE;
    float Cx = 0.f, Cy = 0.f, Fx = 0.f, Fy = 0.f;
#pragma unroll 8
    for (int j = 0; j < CHUNK; ++j) {
      const float4 p  = sP[j];
      const float dx  = xix - p.x;
      const float dy  = xiy - p.y;
      const float d2  = __builtin_fmaf(dx, dx, dy * dy);
      const float g   = __builtin_amdgcn_exp2f(-d2);
      const float wg  = sW[j] * g;
      Cx = __builtin_fmaf(wg, dx, Cx);
      Cy = __builtin_fmaf(wg, dy, Cy);
      Fx = __builtin_fmaf(wg, p.z, Fx);
      Fy = __builtin_fmaf(wg, p.w, Fy);
    }
    pG[(c - NCK) * NAG + i] = make_float4(Cx, Cy, Fx, Fy);
  }
}

__global__ __launch_bounds__(BLOCK) void wm_final_kernel(
    const float4* __restrict__ pK, const float4* __restrict__ pG,
    float2* __restrict__ out) {
  const int i = blockIdx.x * BLOCK + threadIdx.x;
  float A = 0.f, Bx = 0.f, By = 0.f;
#pragma unroll
  for (int c = 0; c < NCK; ++c) {
    const float4 v = pK[c * NAG + i];
    A += v.x; Bx += v.y; By += v.z;
  }
  float Cx = 0.f, Cy = 0.f, Fx = 0.f, Fy = 0.f;
#pragma unroll
  for (int c = 0; c < NCG; ++c) {
    const float4 v = pG[c * NAG + i];
    Cx += v.x; Cy += v.y; Fx += v.z; Fy += v.w;
  }
  const float invA = 1.0f / A;   // A >= 1 (self term), never zero
  const float ox = (SC_B * Bx - SC_C * Cx + SC_F * Fx) * invA;
  const float oy = (SC_B * By - SC_C * Cy + SC_F * Fy) * invA;
  out[i] = make_float2(ox, oy);
}

extern "C" void kernel_launch(void* const* d_in, const int* in_sizes, int n_in,
                              void* d_out, int out_size, void* d_ws, size_t ws_size,
                              hipStream_t stream) {
  const float*  t  = (const float*)d_in[0];
  const float2* X  = (const float2*)d_in[1];
  const float2* m0 = (const float2*)d_in[2];
  const float2* mv = (const float2*)d_in[3];
  const float*  w  = (const float*)d_in[4];
  float4* pK = (float4*)d_ws;                        // 4 MB
  float4* pG = (float4*)((char*)d_ws + (size_t)NCK * NAG * sizeof(float4));  // +2 MB

  dim3 grid(NAG / BLOCK, NCK + NCG);   // 32 x 48 = 1536 blocks, 6/CU
  wm_pair_kernel<<<grid, BLOCK, 0, stream>>>(t, X, m0, mv, w, pK, pG);
  wm_final_kernel<<<NAG / BLOCK, BLOCK, 0, stream>>>(pK, pG, (float2*)d_out);
}